// Round 17
// baseline (300.933 us; speedup 1.0000x reference)
//
#include <hip/hip_runtime.h>
#include <hip/hip_bf16.h>

typedef __attribute__((ext_vector_type(8))) short bf16x8;   // 8 bf16 in 4 VGPRs
typedef __attribute__((ext_vector_type(4))) float f32x4;
typedef unsigned short u16;
typedef unsigned int u32;

#define DEV __device__ __forceinline__

DEV float bf2f(u16 v) { u32 u = ((u32)v) << 16; return __builtin_bit_cast(float, u); }
DEV u16 f2bf(float f) {
    u32 u = __builtin_bit_cast(u32, f);
    u32 r = (u + 0x7FFFu + ((u >> 16) & 1u)) >> 16;
    return (u16)r;
}
DEV u16 f2bf_trunc(float f) { return (u16)(__builtin_bit_cast(u32, f) >> 16); }

DEV void gll16(const u16* g, u16* l) {
    __builtin_amdgcn_global_load_lds((const __attribute__((address_space(1))) void*)g,
                                     (__attribute__((address_space(3))) void*)l, 16, 0, 0);
}

#define WAIT_VM0()   asm volatile("s_waitcnt vmcnt(0)" ::: "memory")
#define WAIT_LGKM0() asm volatile("s_waitcnt lgkmcnt(0)" ::: "memory")
#define BAR()        __builtin_amdgcn_s_barrier()
#define BARF()       asm volatile("s_barrier" ::: "memory")   // barrier + compiler mem fence

// ---------------------------------------------------------------------------
// Fused prep: self-detect dtype + cvt x/Wqkv/Wo to bf16 + rope table. 1 launch.
// (r15-verified) Each block detects independently; block 0 publishes *flag.
// ---------------------------------------------------------------------------
DEV void cvt8(const void* in, u16* out, int i, int fl) {
    if (fl) {
        ((bf16x8*)out)[i] = ((const bf16x8*)in)[i];
    } else {
        float4 a = ((const float4*)in)[2 * i], b = ((const float4*)in)[2 * i + 1];
        bf16x8 o;
        o[0] = (short)f2bf(a.x); o[1] = (short)f2bf(a.y);
        o[2] = (short)f2bf(a.z); o[3] = (short)f2bf(a.w);
        o[4] = (short)f2bf(b.x); o[5] = (short)f2bf(b.y);
        o[6] = (short)f2bf(b.z); o[7] = (short)f2bf(b.w);
        ((bf16x8*)out)[i] = o;
    }
}

__global__ void prep_kernel(const void* __restrict__ x, u16* __restrict__ xb,
                            const void* __restrict__ Wq, u16* __restrict__ Wqb,
                            const void* __restrict__ Wo, u16* __restrict__ Wob,
                            float2* __restrict__ tab, int* __restrict__ flag) {
    __shared__ int cnt;
    if (threadIdx.x == 0) cnt = 0;
    __syncthreads();
    {
        int c = 0;
        for (int i = threadIdx.x; i < 4096; i += 256) {
            u32 w = ((const u32*)x)[i];
            u32 e = (w >> 7) & 0xFF;
            c += (e >= 110 && e <= 132) ? 1 : 0;
        }
        atomicAdd(&cnt, c);
    }
    __syncthreads();
    const int fl = (cnt * 2 > 4096) ? 1 : 0;
    if (blockIdx.x == 0 && threadIdx.x == 0) *flag = fl;

    constexpr int N8X = 1572864, N8W = 393216, N8O = 131072;     // /8 elem counts
    constexpr int C1 = N8X, C2 = N8X + N8W, C3 = N8X + N8W + N8O;
    constexpr int TOTAL = C3 + 768 * 512;
    const int stride = gridDim.x * 256;
    for (int i = blockIdx.x * 256 + threadIdx.x; i < TOTAL; i += stride) {
        if (i < C1)       cvt8(x, xb, i, fl);
        else if (i < C2)  cvt8(Wq, Wqb, i - C1, fl);
        else if (i < C3)  cvt8(Wo, Wob, i - C2, fl);
        else {
            int r = i - C3;
            int t = r >> 9, j = r & 511;
            float freq = expf(-(float)(2 * j) * (9.210340371976184f / 1024.0f));
            float ang = (float)t * freq;
            tab[r] = make_float2(cosf(ang), sinf(ang));
        }
    }
}

// ---------------------------------------------------------------------------
// GEMM 256xBN tile, BK=64, 8 waves (2M x 4N), per-wave 128x(BN/4), 2-buf LDS,
// 4 phases per K-tile (r10/r13-verified skeleton; BN templated: 192 or 256).
// BN=192 for QKV: grid 48x16 = 768 = exactly 3 x 256 CUs -> zero dispatch tail.
// RoPE predicate is per-16-col fragment (a 192-tile can straddle col 2048).
// ---------------------------------------------------------------------------
template<int BN>
__global__ __launch_bounds__(512, 2)
void gemm256p_kernel(const u16* __restrict__ A, const u16* __restrict__ W,
                     const void* __restrict__ bias, void* __restrict__ C,
                     int N, const int* __restrict__ flag, int out_mode,
                     const float2* __restrict__ tab, int rope) {
    constexpr int K = 1024, NT = 16;
    constexpr int NF = BN / 64;                 // B n-frags per wave (3 or 4)
    __shared__ u16 lds[2][16384 + BN * 64];     // per slot: A[256][64] @0, B[BN][64] @16384
    const int tid = threadIdx.x;
    const int l = tid & 63, w = tid >> 6;
    const int wm = w >> 2, wn = w & 3;          // 2M x 4N wave grid
    const int lo = l & 15, hi = l >> 4;

    const int M0 = blockIdx.x * 256, N0 = blockIdx.y * BN;

    const int rS = tid >> 3;                      // 0..63
    const int qS = (tid & 7) ^ (rS & 7);
    const u16* Ag = A + (size_t)(M0 + rS) * K + qS * 8;
    const u16* Wg = W + (size_t)(N0 + rS) * K + qS * 8;
    const int lb = w * 512;                       // wave-uniform u16 base within call-group

    f32x4 acc[8][NF] = {};

#define STG_A(kt, slot, half)                                                  \
    {                                                                          \
        u16* sA_ = &lds[slot][(half) * 8192];                                  \
        const u16* ga_ = Ag + (kt) * 64 + (size_t)(128 * (half)) * K;          \
        gll16(ga_,                  sA_ + lb);                                 \
        gll16(ga_ + (size_t)64 * K, sA_ + 4096 + lb);                          \
    }
#define STG_B(kt, slot)                                                        \
    {                                                                          \
        u16* sB_ = &lds[slot][16384];                                          \
        const u16* gb_ = Wg + (kt) * 64;                                       \
        _Pragma("unroll")                                                      \
        for (int hh = 0; hh < NF; ++hh)                                        \
            gll16(gb_ + (size_t)(64 * hh) * K, sB_ + hh * 4096 + lb);          \
    }

    STG_A(0, 0, 0); STG_A(0, 0, 1);
    STG_B(0, 0);
    WAIT_VM0();
    BARF();

    const int csw = lo & 7;

#pragma unroll 1
    for (int t = 0; t < NT; ++t) {
        const int cur = t & 1, nxt = cur ^ 1;
        const u16* sA = &lds[cur][0];
        const u16* sB = &lds[cur][16384];
        bf16x8 afr[4], bfr[NF];

        // ---- phase 0: ks=0, m-half 0 ----
#pragma unroll
        for (int n = 0; n < NF; ++n)
            bfr[n] = *(const bf16x8*)&sB[(wn * (BN / 4) + n * 16 + lo) * 64 + ((hi ^ csw) * 8)];
#pragma unroll
        for (int m = 0; m < 4; ++m)
            afr[m] = *(const bf16x8*)&sA[(wm * 128 + m * 16 + lo) * 64 + ((hi ^ csw) * 8)];
        if (t + 1 < NT) { STG_A(t + 1, nxt, 0); STG_A(t + 1, nxt, 1); }
        BARF();
        __builtin_amdgcn_s_setprio(1);
#pragma unroll
        for (int m = 0; m < 4; ++m)
#pragma unroll
            for (int n = 0; n < NF; ++n)
                acc[m][n] = __builtin_amdgcn_mfma_f32_16x16x32_bf16(afr[m], bfr[n], acc[m][n], 0, 0, 0);
        __builtin_amdgcn_s_setprio(0);
        BARF();

        // ---- phase 1: ks=0, m-half 1 ----
#pragma unroll
        for (int m = 0; m < 4; ++m)
            afr[m] = *(const bf16x8*)&sA[(wm * 128 + 64 + m * 16 + lo) * 64 + ((hi ^ csw) * 8)];
        if (t + 1 < NT) { STG_B(t + 1, nxt); }
        BARF();
        __builtin_amdgcn_s_setprio(1);
#pragma unroll
        for (int m = 0; m < 4; ++m)
#pragma unroll
            for (int n = 0; n < NF; ++n)
                acc[4 + m][n] = __builtin_amdgcn_mfma_f32_16x16x32_bf16(afr[m], bfr[n], acc[4 + m][n], 0, 0, 0);
        __builtin_amdgcn_s_setprio(0);
        BARF();

        // ---- phase 2: ks=1, m-half 0 ----
#pragma unroll
        for (int n = 0; n < NF; ++n)
            bfr[n] = *(const bf16x8*)&sB[(wn * (BN / 4) + n * 16 + lo) * 64 + (((4 + hi) ^ csw) * 8)];
#pragma unroll
        for (int m = 0; m < 4; ++m)
            afr[m] = *(const bf16x8*)&sA[(wm * 128 + m * 16 + lo) * 64 + (((4 + hi) ^ csw) * 8)];
        BARF();
        __builtin_amdgcn_s_setprio(1);
#pragma unroll
        for (int m = 0; m < 4; ++m)
#pragma unroll
            for (int n = 0; n < NF; ++n)
                acc[m][n] = __builtin_amdgcn_mfma_f32_16x16x32_bf16(afr[m], bfr[n], acc[m][n], 0, 0, 0);
        __builtin_amdgcn_s_setprio(0);
        BARF();

        // ---- phase 3: ks=1, m-half 1 ----
#pragma unroll
        for (int m = 0; m < 4; ++m)
            afr[m] = *(const bf16x8*)&sA[(wm * 128 + 64 + m * 16 + lo) * 64 + (((4 + hi) ^ csw) * 8)];
        WAIT_VM0();                              // own stage loads (issued ph0/ph1) confirmed
        BARF();
        __builtin_amdgcn_s_setprio(1);
#pragma unroll
        for (int m = 0; m < 4; ++m)
#pragma unroll
            for (int n = 0; n < NF; ++n)
                acc[4 + m][n] = __builtin_amdgcn_mfma_f32_16x16x32_bf16(afr[m], bfr[n], acc[4 + m][n], 0, 0, 0);
        __builtin_amdgcn_s_setprio(0);
        BARF();                                  // tile boundary: buf[nxt] globally ready
    }
#undef STG_A
#undef STG_B

    // epilogue: C/D layout col=lane&15, row=(lane>>4)*4+j  [m89-verified]
    const int fl = *flag;
    const int f32out = out_mode ? (fl == 0) : 0;
#pragma unroll
    for (int mi = 0; mi < 8; ++mi) {
        const int rbase = M0 + wm * 128 + (mi >> 2) * 64 + (mi & 3) * 16 + hi * 4;
        const int tbase = (M0 % 768) + wm * 128 + (mi >> 2) * 64 + (mi & 3) * 16 + hi * 4;
#pragma unroll
        for (int n = 0; n < NF; ++n) {
            const int col = N0 + wn * (BN / 4) + lo + n * 16;
            float bi = fl ? bf2f(((const u16*)bias)[col]) : ((const float*)bias)[col];
            const int jf = (col & 1023) >> 1;
            const int odd = col & 1;
            const int do_rope = rope && (col < 2048);   // per-frag (16-aligned, wave-uniform)
#pragma unroll
            for (int j = 0; j < 4; ++j) {
                float v = acc[mi][n][j] + bi;
                if (do_rope) {
                    float partner = __shfl_xor(v, 1);   // adjacent column (lane lo^1)
                    float2 cs = tab[(tbase + j) * 512 + jf];
                    v = odd ? (v * cs.x + partner * cs.y) : (v * cs.x - partner * cs.y);
                }
                size_t idx = (size_t)(rbase + j) * N + col;
                if (f32out) ((float*)C)[idx] = v;
                else        ((u16*)C)[idx] = f2bf(v);
            }
        }
    }
}

// ---------------------------------------------------------------------------
// Flash attention, QBLK=128, 8 waves x 16 rows (r16-verified: XCD-chunked grid).
// ---------------------------------------------------------------------------
__global__ __launch_bounds__(512)
void attn_kernel(const u16* __restrict__ qkv, u16* __restrict__ y) {
    constexpr int T = 768, CH = 1024, QKVC = 3072;
    constexpr float NEG = -30000.0f;
    __shared__ u16 Ks[2][64 * 64];  // [key][d], cols XOR-swizzled by (key&7)*8
    __shared__ u16 Vt[64 * 72];     // [d][key], key-col XOR-swizzled by ((d>>3)&7)*8
    __shared__ u16 Ps[128 * 72];    // [q][key], stride-72

    const int tid = threadIdx.x, l = tid & 63, w = tid >> 6;   // w = 0..7
    // XCD-chunked block remap (grid 1536 = 8 XCD * 192)
    const int hw = blockIdx.x;
    const int xcd = hw & 7, pos = hw >> 3;
    const int qt = pos % 6;
    const int g = (pos / 6) * 8 + xcd;          // (b,h) group, 0..255
    const int h = g & 15, b = g >> 4;
    const int lo = l & 15, hi = l >> 4;
    const int kk = hi * 8;
    const int swzk = (lo & 7) * 8;

    const int qrow = qt * 128 + w * 16 + lo;
    const u16* qptr = qkv + (size_t)(b * T + qrow) * QKVC + h * 64 + kk;
    bf16x8 aq0r = *(const bf16x8*)qptr;
    bf16x8 aq1r = *(const bf16x8*)(qptr + 32);
    bf16x8 aq0, aq1;
#pragma unroll
    for (int e = 0; e < 8; ++e) {
        aq0[e] = (short)f2bf(bf2f((u16)aq0r[e]) * 0.125f);
        aq1[e] = (short)f2bf(bf2f((u16)aq1r[e]) * 0.125f);
    }

    f32x4 o[4] = {};
    float mrun[4] = {NEG, NEG, NEG, NEG};
    float lrun[4] = {0.f, 0.f, 0.f, 0.f};    // per-lane PARTIAL row-sums (reduced in epilogue)

    const int ksr = w * 8 + (l >> 3);
    const int ksc = ((l & 7) ^ ((l >> 3) & 7)) * 8;
    const u16* kbase = qkv + (size_t)(b * T + ksr) * QKVC + CH + h * 64 + ksc;

    const int vd0 = (tid & 7) * 8;
    const int vswz = (tid & 7) * 8;
    const int vr0 = tid >> 3;                    // 0..63
    const u16* vbase = qkv + (size_t)(b * T) * QKVC + 2 * CH + h * 64 + vd0;

    const int NTk = 2 * qt + 2;                  // K-tiles for this block

    gll16(kbase, &Ks[0][w * 512]);
    bf16x8 cv0 = *(const bf16x8*)(vbase + (size_t)vr0 * QKVC);
    WAIT_VM0();
#pragma unroll
    for (int e = 0; e < 8; ++e)
        Vt[(vd0 + e) * 72 + (vr0 ^ vswz)] = (u16)cv0[e];

    for (int kt = 0; kt < NTk; ++kt) {
        const int cur = kt & 1, nxt = cur ^ 1;
        bf16x8 nv0;
        if (kt + 1 < NTk) {
            const size_t koff = (size_t)((kt + 1) * 64) * QKVC;
            gll16(kbase + koff, &Ks[nxt][w * 512]);
            nv0 = *(const bf16x8*)(vbase + (size_t)((kt + 1) * 64 + vr0) * QKVC);
        }
        WAIT_LGKM0();
        BAR();

        __builtin_amdgcn_s_setprio(1);
        f32x4 s[4];
#pragma unroll
        for (int n = 0; n < 4; ++n) {
            bf16x8 kb0 = *(const bf16x8*)&Ks[cur][(n * 16 + lo) * 64 + (kk ^ swzk)];
            bf16x8 kb1 = *(const bf16x8*)&Ks[cur][(n * 16 + lo) * 64 + ((32 + kk) ^ swzk)];
            f32x4 z = {0.f, 0.f, 0.f, 0.f};
            z = __builtin_amdgcn_mfma_f32_16x16x32_bf16(aq0, kb0, z, 0, 0, 0);
            z = __builtin_amdgcn_mfma_f32_16x16x32_bf16(aq1, kb1, z, 0, 0, 0);
            s[n] = z;
        }
        __builtin_amdgcn_s_setprio(0);

        if (kt >= 2 * qt) {   // diagonal-crossing tiles only
#pragma unroll
            for (int n = 0; n < 4; ++n) {
                int kcol = kt * 64 + n * 16 + lo;
#pragma unroll
                for (int j = 0; j < 4; ++j)
                    if (kcol > qt * 128 + w * 16 + hi * 4 + j) s[n][j] = NEG;
            }
        }
        float mx[4];
#pragma unroll
        for (int j = 0; j < 4; ++j) {
            float m0 = fmaxf(fmaxf(s[0][j], s[1][j]), fmaxf(s[2][j], s[3][j]));
            m0 = fmaxf(m0, __shfl_xor(m0, 1));
            m0 = fmaxf(m0, __shfl_xor(m0, 2));
            m0 = fmaxf(m0, __shfl_xor(m0, 4));
            m0 = fmaxf(m0, __shfl_xor(m0, 8));
            mx[j] = m0;
        }
        // defer-max: rescale only when some row grows by > 8
        float gg = fmaxf(fmaxf(mx[0] - mrun[0], mx[1] - mrun[1]),
                         fmaxf(mx[2] - mrun[2], mx[3] - mrun[3]));
        if (!__all(gg <= 8.0f)) {
#pragma unroll
            for (int j = 0; j < 4; ++j) {
                float mn = fmaxf(mrun[j], mx[j]);
                float c = __expf(mrun[j] - mn);
                mrun[j] = mn;
                lrun[j] *= c;
#pragma unroll
                for (int n = 0; n < 4; ++n) o[n][j] *= c;
            }
        }
        float p[4][4];
#pragma unroll
        for (int n = 0; n < 4; ++n)
#pragma unroll
            for (int j = 0; j < 4; ++j) {
                p[n][j] = __expf(s[n][j] - mrun[j]);
                Ps[(w * 16 + hi * 4 + j) * 72 + n * 16 + lo] = f2bf_trunc(p[n][j]);
            }
#pragma unroll
        for (int j = 0; j < 4; ++j)
            lrun[j] += p[0][j] + p[1][j] + p[2][j] + p[3][j];   // per-lane partial

        __builtin_amdgcn_s_setprio(1);
#pragma unroll
        for (int c = 0; c < 2; ++c) {
            bf16x8 pa = *(const bf16x8*)&Ps[(w * 16 + lo) * 72 + c * 32 + kk];
#pragma unroll
            for (int n = 0; n < 4; ++n) {
                const int v = (n * 2 + (lo >> 3)) & 7;
                bf16x8 vb = *(const bf16x8*)&Vt[(n * 16 + lo) * 72 + ((c * 32 + kk) ^ (v * 8))];
                o[n] = __builtin_amdgcn_mfma_f32_16x16x32_bf16(pa, vb, o[n], 0, 0, 0);
            }
        }
        __builtin_amdgcn_s_setprio(0);

        if (kt + 1 < NTk) {
            WAIT_VM0();
            BAR();
#pragma unroll
            for (int e = 0; e < 8; ++e)
                Vt[(vd0 + e) * 72 + (vr0 ^ vswz)] = (u16)nv0[e];
        }
    }

    // epilogue: reduce partial row-sums across the 16-lane row group, normalize
    float inv[4];
#pragma unroll
    for (int j = 0; j < 4; ++j) {
        float r = lrun[j];
        r += __shfl_xor(r, 1);
        r += __shfl_xor(r, 2);
        r += __shfl_xor(r, 4);
        r += __shfl_xor(r, 8);
        inv[j] = (r > 0.f) ? 1.0f / r : 0.f;
    }
#pragma unroll
    for (int n = 0; n < 4; ++n)
#pragma unroll
        for (int j = 0; j < 4; ++j) {
            int t = qt * 128 + w * 16 + hi * 4 + j;
            y[(size_t)(b * T + t) * CH + h * 64 + n * 16 + lo] = f2bf(o[n][j] * inv[j]);
        }
}

// ---------------------------------------------------------------------------
extern "C" void kernel_launch(void* const* d_in, const int* in_sizes, int n_in,
                              void* d_out, int out_size, void* d_ws, size_t ws_size,
                              hipStream_t stream) {
    char* ws = (char*)d_ws;
    int*   flag  = (int*)ws;
    u16*   xb    = (u16*)(ws + 256);
    u16*   Wqb   = (u16*)(ws + 256 + 25165824);
    u16*   Wob   = (u16*)(ws + 256 + 31457280);
    u16*   qkv   = (u16*)(ws + 256 + 33570816);
    u16*   y     = (u16*)(ws + 256 + 109068288);
    float2* tab  = (float2*)(ws + 256 + 134234112);

    prep_kernel<<<2048, 256, 0, stream>>>(d_in[0], xb, d_in[1], Wqb, d_in[3], Wob, tab, flag);

    // QKV GEMM (M=12288, N=3072): 256x192 tiles, grid (48,16)=768=3x256 (no tail), fused bias+RoPE
    gemm256p_kernel<192><<<dim3(48, 16), 512, 0, stream>>>(xb, Wqb, d_in[2], qkv, 3072, flag, 0, tab, 1);
    // Attention: QBLK=128, 1D grid 1536 with XCD-chunked (b,h) grouping
    attn_kernel<<<1536, 512, 0, stream>>>(qkv, y);
    // Output GEMM (M=12288, N=1024): 256x256 tiles, natural grid (48,4)
    gemm256p_kernel<256><<<dim3(48, 4), 512, 0, stream>>>(y, Wob, d_in[4], d_out, 1024, flag, 1, tab, 0);
}

// Round 18
// 278.790 us; speedup vs baseline: 1.0794x; 1.0794x over previous
//
#include <hip/hip_runtime.h>
#include <hip/hip_bf16.h>

typedef __attribute__((ext_vector_type(8))) short bf16x8;   // 8 bf16 in 4 VGPRs
typedef __attribute__((ext_vector_type(4))) float f32x4;
typedef unsigned short u16;
typedef unsigned int u32;

#define DEV __device__ __forceinline__

DEV float bf2f(u16 v) { u32 u = ((u32)v) << 16; return __builtin_bit_cast(float, u); }
DEV u16 f2bf(float f) {
    u32 u = __builtin_bit_cast(u32, f);
    u32 r = (u + 0x7FFFu + ((u >> 16) & 1u)) >> 16;
    return (u16)r;
}
DEV u16 f2bf_trunc(float f) { return (u16)(__builtin_bit_cast(u32, f) >> 16); }

DEV void gll16(const u16* g, u16* l) {
    __builtin_amdgcn_global_load_lds((const __attribute__((address_space(1))) void*)g,
                                     (__attribute__((address_space(3))) void*)l, 16, 0, 0);
}

#define WAIT_VM0()   asm volatile("s_waitcnt vmcnt(0)" ::: "memory")
#define WAIT_LGKM0() asm volatile("s_waitcnt lgkmcnt(0)" ::: "memory")
#define BAR()        __builtin_amdgcn_s_barrier()
#define BARF()       asm volatile("s_barrier" ::: "memory")   // barrier + compiler mem fence

// ---------------------------------------------------------------------------
// Fused prep: self-detect dtype + cvt x/Wqkv/Wo to bf16 + rope table. 1 launch.
// (r15-verified) Each block detects independently; block 0 publishes *flag.
// ---------------------------------------------------------------------------
DEV void cvt8(const void* in, u16* out, int i, int fl) {
    if (fl) {
        ((bf16x8*)out)[i] = ((const bf16x8*)in)[i];
    } else {
        float4 a = ((const float4*)in)[2 * i], b = ((const float4*)in)[2 * i + 1];
        bf16x8 o;
        o[0] = (short)f2bf(a.x); o[1] = (short)f2bf(a.y);
        o[2] = (short)f2bf(a.z); o[3] = (short)f2bf(a.w);
        o[4] = (short)f2bf(b.x); o[5] = (short)f2bf(b.y);
        o[6] = (short)f2bf(b.z); o[7] = (short)f2bf(b.w);
        ((bf16x8*)out)[i] = o;
    }
}

__global__ void prep_kernel(const void* __restrict__ x, u16* __restrict__ xb,
                            const void* __restrict__ Wq, u16* __restrict__ Wqb,
                            const void* __restrict__ Wo, u16* __restrict__ Wob,
                            float2* __restrict__ tab, int* __restrict__ flag) {
    __shared__ int cnt;
    if (threadIdx.x == 0) cnt = 0;
    __syncthreads();
    {
        int c = 0;
        for (int i = threadIdx.x; i < 4096; i += 256) {
            u32 w = ((const u32*)x)[i];
            u32 e = (w >> 7) & 0xFF;
            c += (e >= 110 && e <= 132) ? 1 : 0;
        }
        atomicAdd(&cnt, c);
    }
    __syncthreads();
    const int fl = (cnt * 2 > 4096) ? 1 : 0;
    if (blockIdx.x == 0 && threadIdx.x == 0) *flag = fl;

    constexpr int N8X = 1572864, N8W = 393216, N8O = 131072;     // /8 elem counts
    constexpr int C1 = N8X, C2 = N8X + N8W, C3 = N8X + N8W + N8O;
    constexpr int TOTAL = C3 + 768 * 512;
    const int stride = gridDim.x * 256;
    for (int i = blockIdx.x * 256 + threadIdx.x; i < TOTAL; i += stride) {
        if (i < C1)       cvt8(x, xb, i, fl);
        else if (i < C2)  cvt8(Wq, Wqb, i - C1, fl);
        else if (i < C3)  cvt8(Wo, Wob, i - C2, fl);
        else {
            int r = i - C3;
            int t = r >> 9, j = r & 511;
            float freq = expf(-(float)(2 * j) * (9.210340371976184f / 1024.0f));
            float ang = (float)t * freq;
            tab[r] = make_float2(cosf(ang), sinf(ang));
        }
    }
}

// ---------------------------------------------------------------------------
// GEMM 256x256 tile, BK=64, 8 waves (2M x 4N), per-wave 128x64, 2-buf LDS,
// 4 phases per K-tile (r10/r13/r16-verified best: ~153 us QKV).
// bias read directly from raw input (bf16 or f32 per flag).
// ---------------------------------------------------------------------------
__global__ __launch_bounds__(512, 2)
void gemm256p_kernel(const u16* __restrict__ A, const u16* __restrict__ W,
                     const void* __restrict__ bias, void* __restrict__ C,
                     int N, const int* __restrict__ flag, int out_mode,
                     const float2* __restrict__ tab, int rope) {
    constexpr int K = 1024, NT = 16;
    __shared__ u16 lds[2][32768];   // 131072 B: per slot A @0 (32 KB), B @16384 u16
    const int tid = threadIdx.x;
    const int l = tid & 63, w = tid >> 6;
    const int wm = w >> 2, wn = w & 3;          // 2M x 4N wave grid
    const int lo = l & 15, hi = l >> 4;

    const int M0 = blockIdx.x * 256, N0 = blockIdx.y * 256;

    const int rS = tid >> 3;                      // 0..63
    const int qS = (tid & 7) ^ (rS & 7);
    const u16* Ag = A + (size_t)(M0 + rS) * K + qS * 8;
    const u16* Wg = W + (size_t)(N0 + rS) * K + qS * 8;
    const int lb = w * 512;                       // wave-uniform u16 base within call-group

    f32x4 acc[8][4] = {};

#define STG_A(kt, slot, half)                                                  \
    {                                                                          \
        u16* sA_ = &lds[slot][(half) * 8192];                                  \
        const u16* ga_ = Ag + (kt) * 64 + (size_t)(128 * (half)) * K;          \
        gll16(ga_,                  sA_ + lb);                                 \
        gll16(ga_ + (size_t)64 * K, sA_ + 4096 + lb);                          \
    }
#define STG_B(kt, slot, half)                                                  \
    {                                                                          \
        u16* sB_ = &lds[slot][16384 + (half) * 8192];                          \
        const u16* gb_ = Wg + (kt) * 64 + (size_t)(128 * (half)) * K;          \
        gll16(gb_,                  sB_ + lb);                                 \
        gll16(gb_ + (size_t)64 * K, sB_ + 4096 + lb);                          \
    }

    STG_A(0, 0, 0); STG_A(0, 0, 1);
    STG_B(0, 0, 0); STG_B(0, 0, 1);
    WAIT_VM0();
    BARF();

    const int csw = lo & 7;

#pragma unroll 1
    for (int t = 0; t < NT; ++t) {
        const int cur = t & 1, nxt = cur ^ 1;
        const u16* sA = &lds[cur][0];
        const u16* sB = &lds[cur][16384];
        bf16x8 afr[4], bfr[4];

        // ---- phase 0: ks=0, m-half 0 ----
#pragma unroll
        for (int n = 0; n < 4; ++n)
            bfr[n] = *(const bf16x8*)&sB[(wn * 64 + n * 16 + lo) * 64 + ((hi ^ csw) * 8)];
#pragma unroll
        for (int m = 0; m < 4; ++m)
            afr[m] = *(const bf16x8*)&sA[(wm * 128 + m * 16 + lo) * 64 + ((hi ^ csw) * 8)];
        if (t + 1 < NT) { STG_A(t + 1, nxt, 0); STG_A(t + 1, nxt, 1); }
        BARF();
        __builtin_amdgcn_s_setprio(1);
#pragma unroll
        for (int m = 0; m < 4; ++m)
#pragma unroll
            for (int n = 0; n < 4; ++n)
                acc[m][n] = __builtin_amdgcn_mfma_f32_16x16x32_bf16(afr[m], bfr[n], acc[m][n], 0, 0, 0);
        __builtin_amdgcn_s_setprio(0);
        BARF();

        // ---- phase 1: ks=0, m-half 1 ----
#pragma unroll
        for (int m = 0; m < 4; ++m)
            afr[m] = *(const bf16x8*)&sA[(wm * 128 + 64 + m * 16 + lo) * 64 + ((hi ^ csw) * 8)];
        if (t + 1 < NT) { STG_B(t + 1, nxt, 0); STG_B(t + 1, nxt, 1); }
        BARF();
        __builtin_amdgcn_s_setprio(1);
#pragma unroll
        for (int m = 0; m < 4; ++m)
#pragma unroll
            for (int n = 0; n < 4; ++n)
                acc[4 + m][n] = __builtin_amdgcn_mfma_f32_16x16x32_bf16(afr[m], bfr[n], acc[4 + m][n], 0, 0, 0);
        __builtin_amdgcn_s_setprio(0);
        BARF();

        // ---- phase 2: ks=1, m-half 0 ----
#pragma unroll
        for (int n = 0; n < 4; ++n)
            bfr[n] = *(const bf16x8*)&sB[(wn * 64 + n * 16 + lo) * 64 + (((4 + hi) ^ csw) * 8)];
#pragma unroll
        for (int m = 0; m < 4; ++m)
            afr[m] = *(const bf16x8*)&sA[(wm * 128 + m * 16 + lo) * 64 + (((4 + hi) ^ csw) * 8)];
        BARF();
        __builtin_amdgcn_s_setprio(1);
#pragma unroll
        for (int m = 0; m < 4; ++m)
#pragma unroll
            for (int n = 0; n < 4; ++n)
                acc[m][n] = __builtin_amdgcn_mfma_f32_16x16x32_bf16(afr[m], bfr[n], acc[m][n], 0, 0, 0);
        __builtin_amdgcn_s_setprio(0);
        BARF();

        // ---- phase 3: ks=1, m-half 1 ----
#pragma unroll
        for (int m = 0; m < 4; ++m)
            afr[m] = *(const bf16x8*)&sA[(wm * 128 + 64 + m * 16 + lo) * 64 + (((4 + hi) ^ csw) * 8)];
        WAIT_VM0();                              // own 8 stage loads (issued ph0/ph1) confirmed
        BARF();
        __builtin_amdgcn_s_setprio(1);
#pragma unroll
        for (int m = 0; m < 4; ++m)
#pragma unroll
            for (int n = 0; n < 4; ++n)
                acc[4 + m][n] = __builtin_amdgcn_mfma_f32_16x16x32_bf16(afr[m], bfr[n], acc[4 + m][n], 0, 0, 0);
        __builtin_amdgcn_s_setprio(0);
        BARF();                                  // tile boundary: buf[nxt] globally ready
    }
#undef STG_A
#undef STG_B

    // epilogue: C/D layout col=lane&15, row=(lane>>4)*4+j  [m89-verified]
    const int fl = *flag;
    const int f32out = out_mode ? (fl == 0) : 0;
    const int do_rope = rope && (N0 < 2048);
#pragma unroll
    for (int mi = 0; mi < 8; ++mi) {
        const int rbase = M0 + wm * 128 + (mi >> 2) * 64 + (mi & 3) * 16 + hi * 4;
        const int tbase = (M0 % 768) + wm * 128 + (mi >> 2) * 64 + (mi & 3) * 16 + hi * 4;
#pragma unroll
        for (int n = 0; n < 4; ++n) {
            const int col = N0 + wn * 64 + lo + n * 16;
            float bi = fl ? bf2f(((const u16*)bias)[col]) : ((const float*)bias)[col];
            const int jf = (col & 1023) >> 1;
            const int odd = col & 1;
#pragma unroll
            for (int j = 0; j < 4; ++j) {
                float v = acc[mi][n][j] + bi;
                if (do_rope) {
                    float partner = __shfl_xor(v, 1);   // adjacent column (lane lo^1)
                    float2 cs = tab[(tbase + j) * 512 + jf];
                    v = odd ? (v * cs.x + partner * cs.y) : (v * cs.x - partner * cs.y);
                }
                size_t idx = (size_t)(rbase + j) * N + col;
                if (f32out) ((float*)C)[idx] = v;
                else        ((u16*)C)[idx] = f2bf(v);
            }
        }
    }
}

// ---------------------------------------------------------------------------
// Flash attention, QBLK=128, 8 waves x 16 rows (r13-verified body).
// 1D grid 1536 with XCD-chunked remap: all 6 qt-blocks of one (b,h) land on
// the same XCD (blockIdx%8) so shared K/V panels stay L2-resident (T1).
// Bijective: hw=(pos,xcd); q=pos%6, g=(pos/6)*8+xcd covers (g,q) exactly once.
// ---------------------------------------------------------------------------
__global__ __launch_bounds__(512)
void attn_kernel(const u16* __restrict__ qkv, u16* __restrict__ y) {
    constexpr int T = 768, CH = 1024, QKVC = 3072;
    constexpr float NEG = -30000.0f;
    __shared__ u16 Ks[2][64 * 64];  // [key][d], cols XOR-swizzled by (key&7)*8
    __shared__ u16 Vt[64 * 72];     // [d][key], key-col XOR-swizzled by ((d>>3)&7)*8
    __shared__ u16 Ps[128 * 72];    // [q][key], stride-72

    const int tid = threadIdx.x, l = tid & 63, w = tid >> 6;   // w = 0..7
    // XCD-chunked block remap (grid 1536 = 8 XCD * 192)
    const int hw = blockIdx.x;
    const int xcd = hw & 7, pos = hw >> 3;
    const int qt = pos % 6;
    const int g = (pos / 6) * 8 + xcd;          // (b,h) group, 0..255
    const int h = g & 15, b = g >> 4;
    const int lo = l & 15, hi = l >> 4;
    const int kk = hi * 8;
    const int swzk = (lo & 7) * 8;

    const int qrow = qt * 128 + w * 16 + lo;
    const u16* qptr = qkv + (size_t)(b * T + qrow) * QKVC + h * 64 + kk;
    bf16x8 aq0r = *(const bf16x8*)qptr;
    bf16x8 aq1r = *(const bf16x8*)(qptr + 32);
    bf16x8 aq0, aq1;
#pragma unroll
    for (int e = 0; e < 8; ++e) {
        aq0[e] = (short)f2bf(bf2f((u16)aq0r[e]) * 0.125f);
        aq1[e] = (short)f2bf(bf2f((u16)aq1r[e]) * 0.125f);
    }

    f32x4 o[4] = {};
    float mrun[4] = {NEG, NEG, NEG, NEG};
    float lrun[4] = {0.f, 0.f, 0.f, 0.f};    // per-lane PARTIAL row-sums (reduced in epilogue)

    const int ksr = w * 8 + (l >> 3);
    const int ksc = ((l & 7) ^ ((l >> 3) & 7)) * 8;
    const u16* kbase = qkv + (size_t)(b * T + ksr) * QKVC + CH + h * 64 + ksc;

    const int vd0 = (tid & 7) * 8;
    const int vswz = (tid & 7) * 8;
    const int vr0 = tid >> 3;                    // 0..63
    const u16* vbase = qkv + (size_t)(b * T) * QKVC + 2 * CH + h * 64 + vd0;

    const int NTk = 2 * qt + 2;                  // K-tiles for this block

    gll16(kbase, &Ks[0][w * 512]);
    bf16x8 cv0 = *(const bf16x8*)(vbase + (size_t)vr0 * QKVC);
    WAIT_VM0();
#pragma unroll
    for (int e = 0; e < 8; ++e)
        Vt[(vd0 + e) * 72 + (vr0 ^ vswz)] = (u16)cv0[e];

    for (int kt = 0; kt < NTk; ++kt) {
        const int cur = kt & 1, nxt = cur ^ 1;
        bf16x8 nv0;
        if (kt + 1 < NTk) {
            const size_t koff = (size_t)((kt + 1) * 64) * QKVC;
            gll16(kbase + koff, &Ks[nxt][w * 512]);
            nv0 = *(const bf16x8*)(vbase + (size_t)((kt + 1) * 64 + vr0) * QKVC);
        }
        WAIT_LGKM0();
        BAR();

        __builtin_amdgcn_s_setprio(1);
        f32x4 s[4];
#pragma unroll
        for (int n = 0; n < 4; ++n) {
            bf16x8 kb0 = *(const bf16x8*)&Ks[cur][(n * 16 + lo) * 64 + (kk ^ swzk)];
            bf16x8 kb1 = *(const bf16x8*)&Ks[cur][(n * 16 + lo) * 64 + ((32 + kk) ^ swzk)];
            f32x4 z = {0.f, 0.f, 0.f, 0.f};
            z = __builtin_amdgcn_mfma_f32_16x16x32_bf16(aq0, kb0, z, 0, 0, 0);
            z = __builtin_amdgcn_mfma_f32_16x16x32_bf16(aq1, kb1, z, 0, 0, 0);
            s[n] = z;
        }
        __builtin_amdgcn_s_setprio(0);

        if (kt >= 2 * qt) {   // diagonal-crossing tiles only
#pragma unroll
            for (int n = 0; n < 4; ++n) {
                int kcol = kt * 64 + n * 16 + lo;
#pragma unroll
                for (int j = 0; j < 4; ++j)
                    if (kcol > qt * 128 + w * 16 + hi * 4 + j) s[n][j] = NEG;
            }
        }
        float mx[4];
#pragma unroll
        for (int j = 0; j < 4; ++j) {
            float m0 = fmaxf(fmaxf(s[0][j], s[1][j]), fmaxf(s[2][j], s[3][j]));
            m0 = fmaxf(m0, __shfl_xor(m0, 1));
            m0 = fmaxf(m0, __shfl_xor(m0, 2));
            m0 = fmaxf(m0, __shfl_xor(m0, 4));
            m0 = fmaxf(m0, __shfl_xor(m0, 8));
            mx[j] = m0;
        }
        // defer-max: rescale only when some row grows by > 8
        float gg = fmaxf(fmaxf(mx[0] - mrun[0], mx[1] - mrun[1]),
                         fmaxf(mx[2] - mrun[2], mx[3] - mrun[3]));
        if (!__all(gg <= 8.0f)) {
#pragma unroll
            for (int j = 0; j < 4; ++j) {
                float mn = fmaxf(mrun[j], mx[j]);
                float c = __expf(mrun[j] - mn);
                mrun[j] = mn;
                lrun[j] *= c;
#pragma unroll
                for (int n = 0; n < 4; ++n) o[n][j] *= c;
            }
        }
        float p[4][4];
#pragma unroll
        for (int n = 0; n < 4; ++n)
#pragma unroll
            for (int j = 0; j < 4; ++j) {
                p[n][j] = __expf(s[n][j] - mrun[j]);
                Ps[(w * 16 + hi * 4 + j) * 72 + n * 16 + lo] = f2bf_trunc(p[n][j]);
            }
#pragma unroll
        for (int j = 0; j < 4; ++j)
            lrun[j] += p[0][j] + p[1][j] + p[2][j] + p[3][j];   // per-lane partial

        __builtin_amdgcn_s_setprio(1);
#pragma unroll
        for (int c = 0; c < 2; ++c) {
            bf16x8 pa = *(const bf16x8*)&Ps[(w * 16 + lo) * 72 + c * 32 + kk];
#pragma unroll
            for (int n = 0; n < 4; ++n) {
                const int v = (n * 2 + (lo >> 3)) & 7;
                bf16x8 vb = *(const bf16x8*)&Vt[(n * 16 + lo) * 72 + ((c * 32 + kk) ^ (v * 8))];
                o[n] = __builtin_amdgcn_mfma_f32_16x16x32_bf16(pa, vb, o[n], 0, 0, 0);
            }
        }
        __builtin_amdgcn_s_setprio(0);

        if (kt + 1 < NTk) {
            WAIT_VM0();
            BAR();
#pragma unroll
            for (int e = 0; e < 8; ++e)
                Vt[(vd0 + e) * 72 + (vr0 ^ vswz)] = (u16)nv0[e];
        }
    }

    // epilogue: reduce partial row-sums across the 16-lane row group, normalize
    float inv[4];
#pragma unroll
    for (int j = 0; j < 4; ++j) {
        float r = lrun[j];
        r += __shfl_xor(r, 1);
        r += __shfl_xor(r, 2);
        r += __shfl_xor(r, 4);
        r += __shfl_xor(r, 8);
        inv[j] = (r > 0.f) ? 1.0f / r : 0.f;
    }
#pragma unroll
    for (int n = 0; n < 4; ++n)
#pragma unroll
        for (int j = 0; j < 4; ++j) {
            int t = qt * 128 + w * 16 + hi * 4 + j;
            y[(size_t)(b * T + t) * CH + h * 64 + n * 16 + lo] = f2bf(o[n][j] * inv[j]);
        }
}

// ---------------------------------------------------------------------------
extern "C" void kernel_launch(void* const* d_in, const int* in_sizes, int n_in,
                              void* d_out, int out_size, void* d_ws, size_t ws_size,
                              hipStream_t stream) {
    char* ws = (char*)d_ws;
    int*   flag  = (int*)ws;
    u16*   xb    = (u16*)(ws + 256);
    u16*   Wqb   = (u16*)(ws + 256 + 25165824);
    u16*   Wob   = (u16*)(ws + 256 + 31457280);
    u16*   qkv   = (u16*)(ws + 256 + 33570816);
    u16*   y     = (u16*)(ws + 256 + 109068288);
    float2* tab  = (float2*)(ws + 256 + 134234112);

    prep_kernel<<<2048, 256, 0, stream>>>(d_in[0], xb, d_in[1], Wqb, d_in[3], Wob, tab, flag);

    // QKV GEMM (M=12288, N=3072): 256x256 tiles BK=64, natural grid (48,12), fused bias+RoPE
    gemm256p_kernel<<<dim3(48, 12), 512, 0, stream>>>(xb, Wqb, d_in[2], qkv, 3072, flag, 0, tab, 1);
    // Attention: QBLK=128, 1D grid 1536 with XCD-chunked (b,h) grouping
    attn_kernel<<<1536, 512, 0, stream>>>(qkv, y);
    // Output GEMM (M=12288, N=1024): 256x256 tiles, natural grid (48,4)
    gemm256p_kernel<<<dim3(48, 4), 512, 0, stream>>>(y, Wob, d_in[4], d_out, 1024, flag, 1, tab, 0);
}

// Round 19
// 274.926 us; speedup vs baseline: 1.0946x; 1.0141x over previous
//
#include <hip/hip_runtime.h>
#include <hip/hip_bf16.h>

typedef __attribute__((ext_vector_type(8))) short bf16x8;   // 8 bf16 in 4 VGPRs
typedef __attribute__((ext_vector_type(4))) float f32x4;
typedef unsigned short u16;
typedef unsigned int u32;

#define DEV __device__ __forceinline__

DEV float bf2f(u16 v) { u32 u = ((u32)v) << 16; return __builtin_bit_cast(float, u); }
DEV u16 f2bf(float f) {
    u32 u = __builtin_bit_cast(u32, f);
    u32 r = (u + 0x7FFFu + ((u >> 16) & 1u)) >> 16;
    return (u16)r;
}
DEV u16 f2bf_trunc(float f) { return (u16)(__builtin_bit_cast(u32, f) >> 16); }

DEV void gll16(const u16* g, u16* l) {
    __builtin_amdgcn_global_load_lds((const __attribute__((address_space(1))) void*)g,
                                     (__attribute__((address_space(3))) void*)l, 16, 0, 0);
}

#define WAIT_VM0()   asm volatile("s_waitcnt vmcnt(0)" ::: "memory")
#define WAIT_LGKM0() asm volatile("s_waitcnt lgkmcnt(0)" ::: "memory")
#define BAR()        __builtin_amdgcn_s_barrier()
#define BARF()       asm volatile("s_barrier" ::: "memory")   // barrier + compiler mem fence

// ---------------------------------------------------------------------------
// Fused prep: self-detect dtype + cvt x/Wqkv/Wo to bf16 + rope table. 1 launch.
// (r15-verified) Each block detects independently; block 0 publishes *flag.
// ---------------------------------------------------------------------------
DEV void cvt8(const void* in, u16* out, int i, int fl) {
    if (fl) {
        ((bf16x8*)out)[i] = ((const bf16x8*)in)[i];
    } else {
        float4 a = ((const float4*)in)[2 * i], b = ((const float4*)in)[2 * i + 1];
        bf16x8 o;
        o[0] = (short)f2bf(a.x); o[1] = (short)f2bf(a.y);
        o[2] = (short)f2bf(a.z); o[3] = (short)f2bf(a.w);
        o[4] = (short)f2bf(b.x); o[5] = (short)f2bf(b.y);
        o[6] = (short)f2bf(b.z); o[7] = (short)f2bf(b.w);
        ((bf16x8*)out)[i] = o;
    }
}

__global__ void prep_kernel(const void* __restrict__ x, u16* __restrict__ xb,
                            const void* __restrict__ Wq, u16* __restrict__ Wqb,
                            const void* __restrict__ Wo, u16* __restrict__ Wob,
                            float2* __restrict__ tab, int* __restrict__ flag) {
    __shared__ int cnt;
    if (threadIdx.x == 0) cnt = 0;
    __syncthreads();
    {
        int c = 0;
        for (int i = threadIdx.x; i < 4096; i += 256) {
            u32 w = ((const u32*)x)[i];
            u32 e = (w >> 7) & 0xFF;
            c += (e >= 110 && e <= 132) ? 1 : 0;
        }
        atomicAdd(&cnt, c);
    }
    __syncthreads();
    const int fl = (cnt * 2 > 4096) ? 1 : 0;
    if (blockIdx.x == 0 && threadIdx.x == 0) *flag = fl;

    constexpr int N8X = 1572864, N8W = 393216, N8O = 131072;     // /8 elem counts
    constexpr int C1 = N8X, C2 = N8X + N8W, C3 = N8X + N8W + N8O;
    constexpr int TOTAL = C3 + 768 * 512;
    const int stride = gridDim.x * 256;
    for (int i = blockIdx.x * 256 + threadIdx.x; i < TOTAL; i += stride) {
        if (i < C1)       cvt8(x, xb, i, fl);
        else if (i < C2)  cvt8(Wq, Wqb, i - C1, fl);
        else if (i < C3)  cvt8(Wo, Wob, i - C2, fl);
        else {
            int r = i - C3;
            int t = r >> 9, j = r & 511;
            float freq = expf(-(float)(2 * j) * (9.210340371976184f / 1024.0f));
            float ang = (float)t * freq;
            tab[r] = make_float2(cosf(ang), sinf(ang));
        }
    }
}

// ---------------------------------------------------------------------------
// GEMM BMx256 tile, BK=64, 8 waves (2M x 4N), per-wave (BM/2)x64, 2-buf LDS,
// 4 phases per K-tile (r10/r13/r16-verified skeleton; BM templated 256 or 192).
// BM=192 for out-proj: grid (64,4) = 256 blocks = exactly one dispatch round.
// MH = BM/64 m-frags per half; per-wave rows BM/2; half1 offset BM/4.
// bias read directly from raw input (bf16 or f32 per flag).
// ---------------------------------------------------------------------------
template<int BM>
__global__ __launch_bounds__(512, 2)
void gemm256p_kernel(const u16* __restrict__ A, const u16* __restrict__ W,
                     const void* __restrict__ bias, void* __restrict__ C,
                     int N, const int* __restrict__ flag, int out_mode,
                     const float2* __restrict__ tab, int rope) {
    constexpr int K = 1024, NT = 16;
    constexpr int MH = BM / 64;                 // m-frags per half (4 or 3)
    constexpr int NA = BM / 64;                 // A-stage gll16 calls (64 rows each)
    constexpr int SBOFF = BM * 64;              // B offset within slot (u16)
    __shared__ u16 lds[2][BM * 64 + 16384];     // per slot: A[BM][64], B[256][64]
    const int tid = threadIdx.x;
    const int l = tid & 63, w = tid >> 6;
    const int wm = w >> 2, wn = w & 3;          // 2M x 4N wave grid
    const int lo = l & 15, hi = l >> 4;

    const int M0 = blockIdx.x * BM, N0 = blockIdx.y * 256;

    const int rS = tid >> 3;                      // 0..63
    const int qS = (tid & 7) ^ (rS & 7);
    const u16* Ag = A + (size_t)(M0 + rS) * K + qS * 8;
    const u16* Wg = W + (size_t)(N0 + rS) * K + qS * 8;
    const int lb = w * 512;                       // wave-uniform u16 base within call-group

    f32x4 acc[2 * MH][4] = {};

#define STG_A(kt, slot)                                                        \
    {                                                                          \
        u16* sA_ = &lds[slot][0];                                              \
        const u16* ga_ = Ag + (kt) * 64;                                       \
        _Pragma("unroll")                                                      \
        for (int hh = 0; hh < NA; ++hh)                                        \
            gll16(ga_ + (size_t)(64 * hh) * K, sA_ + hh * 4096 + lb);          \
    }
#define STG_B(kt, slot, half)                                                  \
    {                                                                          \
        u16* sB_ = &lds[slot][SBOFF + (half) * 8192];                          \
        const u16* gb_ = Wg + (kt) * 64 + (size_t)(128 * (half)) * K;          \
        gll16(gb_,                  sB_ + lb);                                 \
        gll16(gb_ + (size_t)64 * K, sB_ + 4096 + lb);                          \
    }

    STG_A(0, 0);
    STG_B(0, 0, 0); STG_B(0, 0, 1);
    WAIT_VM0();
    BARF();

    const int csw = lo & 7;

#pragma unroll 1
    for (int t = 0; t < NT; ++t) {
        const int cur = t & 1, nxt = cur ^ 1;
        const u16* sA = &lds[cur][0];
        const u16* sB = &lds[cur][SBOFF];
        bf16x8 afr[MH], bfr[4];

        // ---- phase 0: ks=0, m-half 0 ----
#pragma unroll
        for (int n = 0; n < 4; ++n)
            bfr[n] = *(const bf16x8*)&sB[(wn * 64 + n * 16 + lo) * 64 + ((hi ^ csw) * 8)];
#pragma unroll
        for (int m = 0; m < MH; ++m)
            afr[m] = *(const bf16x8*)&sA[(wm * (BM / 2) + m * 16 + lo) * 64 + ((hi ^ csw) * 8)];
        if (t + 1 < NT) { STG_A(t + 1, nxt); }
        BARF();
        __builtin_amdgcn_s_setprio(1);
#pragma unroll
        for (int m = 0; m < MH; ++m)
#pragma unroll
            for (int n = 0; n < 4; ++n)
                acc[m][n] = __builtin_amdgcn_mfma_f32_16x16x32_bf16(afr[m], bfr[n], acc[m][n], 0, 0, 0);
        __builtin_amdgcn_s_setprio(0);
        BARF();

        // ---- phase 1: ks=0, m-half 1 ----
#pragma unroll
        for (int m = 0; m < MH; ++m)
            afr[m] = *(const bf16x8*)&sA[(wm * (BM / 2) + BM / 4 + m * 16 + lo) * 64 + ((hi ^ csw) * 8)];
        if (t + 1 < NT) { STG_B(t + 1, nxt, 0); STG_B(t + 1, nxt, 1); }
        BARF();
        __builtin_amdgcn_s_setprio(1);
#pragma unroll
        for (int m = 0; m < MH; ++m)
#pragma unroll
            for (int n = 0; n < 4; ++n)
                acc[MH + m][n] = __builtin_amdgcn_mfma_f32_16x16x32_bf16(afr[m], bfr[n], acc[MH + m][n], 0, 0, 0);
        __builtin_amdgcn_s_setprio(0);
        BARF();

        // ---- phase 2: ks=1, m-half 0 ----
#pragma unroll
        for (int n = 0; n < 4; ++n)
            bfr[n] = *(const bf16x8*)&sB[(wn * 64 + n * 16 + lo) * 64 + (((4 + hi) ^ csw) * 8)];
#pragma unroll
        for (int m = 0; m < MH; ++m)
            afr[m] = *(const bf16x8*)&sA[(wm * (BM / 2) + m * 16 + lo) * 64 + (((4 + hi) ^ csw) * 8)];
        BARF();
        __builtin_amdgcn_s_setprio(1);
#pragma unroll
        for (int m = 0; m < MH; ++m)
#pragma unroll
            for (int n = 0; n < 4; ++n)
                acc[m][n] = __builtin_amdgcn_mfma_f32_16x16x32_bf16(afr[m], bfr[n], acc[m][n], 0, 0, 0);
        __builtin_amdgcn_s_setprio(0);
        BARF();

        // ---- phase 3: ks=1, m-half 1 ----
#pragma unroll
        for (int m = 0; m < MH; ++m)
            afr[m] = *(const bf16x8*)&sA[(wm * (BM / 2) + BM / 4 + m * 16 + lo) * 64 + (((4 + hi) ^ csw) * 8)];
        WAIT_VM0();                              // own stage loads (issued ph0/ph1) confirmed
        BARF();
        __builtin_amdgcn_s_setprio(1);
#pragma unroll
        for (int m = 0; m < MH; ++m)
#pragma unroll
            for (int n = 0; n < 4; ++n)
                acc[MH + m][n] = __builtin_amdgcn_mfma_f32_16x16x32_bf16(afr[m], bfr[n], acc[MH + m][n], 0, 0, 0);
        __builtin_amdgcn_s_setprio(0);
        BARF();                                  // tile boundary: buf[nxt] globally ready
    }
#undef STG_A
#undef STG_B

    // epilogue: C/D layout col=lane&15, row=(lane>>4)*4+j  [m89-verified]
    const int fl = *flag;
    const int f32out = out_mode ? (fl == 0) : 0;
    const int do_rope = rope && (N0 < 2048);
#pragma unroll
    for (int mi = 0; mi < 2 * MH; ++mi) {
        const int grp = mi / MH, idx = mi % MH;
        const int roff = wm * (BM / 2) + grp * (BM / 4) + idx * 16 + hi * 4;
        const int rbase = M0 + roff;
        const int tbase = (M0 % 768) + roff;     // BM | 768 => tile within one batch
#pragma unroll
        for (int n = 0; n < 4; ++n) {
            const int col = N0 + wn * 64 + lo + n * 16;
            float bi = fl ? bf2f(((const u16*)bias)[col]) : ((const float*)bias)[col];
            const int jf = (col & 1023) >> 1;
            const int odd = col & 1;
#pragma unroll
            for (int j = 0; j < 4; ++j) {
                float v = acc[mi][n][j] + bi;
                if (do_rope) {
                    float partner = __shfl_xor(v, 1);   // adjacent column (lane lo^1)
                    float2 cs = tab[(tbase + j) * 512 + jf];
                    v = odd ? (v * cs.x + partner * cs.y) : (v * cs.x - partner * cs.y);
                }
                size_t idx2 = (size_t)(rbase + j) * N + col;
                if (f32out) ((float*)C)[idx2] = v;
                else        ((u16*)C)[idx2] = f2bf(v);
            }
        }
    }
}

// ---------------------------------------------------------------------------
// Flash attention, QBLK=128, 8 waves x 16 rows (r13-verified body).
// 1D grid 1536 with XCD-chunked remap (r16-verified, -16 us).
// ---------------------------------------------------------------------------
__global__ __launch_bounds__(512)
void attn_kernel(const u16* __restrict__ qkv, u16* __restrict__ y) {
    constexpr int T = 768, CH = 1024, QKVC = 3072;
    constexpr float NEG = -30000.0f;
    __shared__ u16 Ks[2][64 * 64];  // [key][d], cols XOR-swizzled by (key&7)*8
    __shared__ u16 Vt[64 * 72];     // [d][key], key-col XOR-swizzled by ((d>>3)&7)*8
    __shared__ u16 Ps[128 * 72];    // [q][key], stride-72

    const int tid = threadIdx.x, l = tid & 63, w = tid >> 6;   // w = 0..7
    const int hw = blockIdx.x;
    const int xcd = hw & 7, pos = hw >> 3;
    const int qt = pos % 6;
    const int g = (pos / 6) * 8 + xcd;          // (b,h) group, 0..255
    const int h = g & 15, b = g >> 4;
    const int lo = l & 15, hi = l >> 4;
    const int kk = hi * 8;
    const int swzk = (lo & 7) * 8;

    const int qrow = qt * 128 + w * 16 + lo;
    const u16* qptr = qkv + (size_t)(b * T + qrow) * QKVC + h * 64 + kk;
    bf16x8 aq0r = *(const bf16x8*)qptr;
    bf16x8 aq1r = *(const bf16x8*)(qptr + 32);
    bf16x8 aq0, aq1;
#pragma unroll
    for (int e = 0; e < 8; ++e) {
        aq0[e] = (short)f2bf(bf2f((u16)aq0r[e]) * 0.125f);
        aq1[e] = (short)f2bf(bf2f((u16)aq1r[e]) * 0.125f);
    }

    f32x4 o[4] = {};
    float mrun[4] = {NEG, NEG, NEG, NEG};
    float lrun[4] = {0.f, 0.f, 0.f, 0.f};    // per-lane PARTIAL row-sums (reduced in epilogue)

    const int ksr = w * 8 + (l >> 3);
    const int ksc = ((l & 7) ^ ((l >> 3) & 7)) * 8;
    const u16* kbase = qkv + (size_t)(b * T + ksr) * QKVC + CH + h * 64 + ksc;

    const int vd0 = (tid & 7) * 8;
    const int vswz = (tid & 7) * 8;
    const int vr0 = tid >> 3;                    // 0..63
    const u16* vbase = qkv + (size_t)(b * T) * QKVC + 2 * CH + h * 64 + vd0;

    const int NTk = 2 * qt + 2;                  // K-tiles for this block

    gll16(kbase, &Ks[0][w * 512]);
    bf16x8 cv0 = *(const bf16x8*)(vbase + (size_t)vr0 * QKVC);
    WAIT_VM0();
#pragma unroll
    for (int e = 0; e < 8; ++e)
        Vt[(vd0 + e) * 72 + (vr0 ^ vswz)] = (u16)cv0[e];

    for (int kt = 0; kt < NTk; ++kt) {
        const int cur = kt & 1, nxt = cur ^ 1;
        bf16x8 nv0;
        if (kt + 1 < NTk) {
            const size_t koff = (size_t)((kt + 1) * 64) * QKVC;
            gll16(kbase + koff, &Ks[nxt][w * 512]);
            nv0 = *(const bf16x8*)(vbase + (size_t)((kt + 1) * 64 + vr0) * QKVC);
        }
        WAIT_LGKM0();
        BAR();

        __builtin_amdgcn_s_setprio(1);
        f32x4 s[4];
#pragma unroll
        for (int n = 0; n < 4; ++n) {
            bf16x8 kb0 = *(const bf16x8*)&Ks[cur][(n * 16 + lo) * 64 + (kk ^ swzk)];
            bf16x8 kb1 = *(const bf16x8*)&Ks[cur][(n * 16 + lo) * 64 + ((32 + kk) ^ swzk)];
            f32x4 z = {0.f, 0.f, 0.f, 0.f};
            z = __builtin_amdgcn_mfma_f32_16x16x32_bf16(aq0, kb0, z, 0, 0, 0);
            z = __builtin_amdgcn_mfma_f32_16x16x32_bf16(aq1, kb1, z, 0, 0, 0);
            s[n] = z;
        }
        __builtin_amdgcn_s_setprio(0);

        if (kt >= 2 * qt) {   // diagonal-crossing tiles only
#pragma unroll
            for (int n = 0; n < 4; ++n) {
                int kcol = kt * 64 + n * 16 + lo;
#pragma unroll
                for (int j = 0; j < 4; ++j)
                    if (kcol > qt * 128 + w * 16 + hi * 4 + j) s[n][j] = NEG;
            }
        }
        float mx[4];
#pragma unroll
        for (int j = 0; j < 4; ++j) {
            float m0 = fmaxf(fmaxf(s[0][j], s[1][j]), fmaxf(s[2][j], s[3][j]));
            m0 = fmaxf(m0, __shfl_xor(m0, 1));
            m0 = fmaxf(m0, __shfl_xor(m0, 2));
            m0 = fmaxf(m0, __shfl_xor(m0, 4));
            m0 = fmaxf(m0, __shfl_xor(m0, 8));
            mx[j] = m0;
        }
        // defer-max: rescale only when some row grows by > 8
        float gg = fmaxf(fmaxf(mx[0] - mrun[0], mx[1] - mrun[1]),
                         fmaxf(mx[2] - mrun[2], mx[3] - mrun[3]));
        if (!__all(gg <= 8.0f)) {
#pragma unroll
            for (int j = 0; j < 4; ++j) {
                float mn = fmaxf(mrun[j], mx[j]);
                float c = __expf(mrun[j] - mn);
                mrun[j] = mn;
                lrun[j] *= c;
#pragma unroll
                for (int n = 0; n < 4; ++n) o[n][j] *= c;
            }
        }
        float p[4][4];
#pragma unroll
        for (int n = 0; n < 4; ++n)
#pragma unroll
            for (int j = 0; j < 4; ++j) {
                p[n][j] = __expf(s[n][j] - mrun[j]);
                Ps[(w * 16 + hi * 4 + j) * 72 + n * 16 + lo] = f2bf_trunc(p[n][j]);
            }
#pragma unroll
        for (int j = 0; j < 4; ++j)
            lrun[j] += p[0][j] + p[1][j] + p[2][j] + p[3][j];   // per-lane partial

        __builtin_amdgcn_s_setprio(1);
#pragma unroll
        for (int c = 0; c < 2; ++c) {
            bf16x8 pa = *(const bf16x8*)&Ps[(w * 16 + lo) * 72 + c * 32 + kk];
#pragma unroll
            for (int n = 0; n < 4; ++n) {
                const int v = (n * 2 + (lo >> 3)) & 7;
                bf16x8 vb = *(const bf16x8*)&Vt[(n * 16 + lo) * 72 + ((c * 32 + kk) ^ (v * 8))];
                o[n] = __builtin_amdgcn_mfma_f32_16x16x32_bf16(pa, vb, o[n], 0, 0, 0);
            }
        }
        __builtin_amdgcn_s_setprio(0);

        if (kt + 1 < NTk) {
            WAIT_VM0();
            BAR();
#pragma unroll
            for (int e = 0; e < 8; ++e)
                Vt[(vd0 + e) * 72 + (vr0 ^ vswz)] = (u16)nv0[e];
        }
    }

    // epilogue: reduce partial row-sums across the 16-lane row group, normalize
    float inv[4];
#pragma unroll
    for (int j = 0; j < 4; ++j) {
        float r = lrun[j];
        r += __shfl_xor(r, 1);
        r += __shfl_xor(r, 2);
        r += __shfl_xor(r, 4);
        r += __shfl_xor(r, 8);
        inv[j] = (r > 0.f) ? 1.0f / r : 0.f;
    }
#pragma unroll
    for (int n = 0; n < 4; ++n)
#pragma unroll
        for (int j = 0; j < 4; ++j) {
            int t = qt * 128 + w * 16 + hi * 4 + j;
            y[(size_t)(b * T + t) * CH + h * 64 + n * 16 + lo] = f2bf(o[n][j] * inv[j]);
        }
}

// ---------------------------------------------------------------------------
extern "C" void kernel_launch(void* const* d_in, const int* in_sizes, int n_in,
                              void* d_out, int out_size, void* d_ws, size_t ws_size,
                              hipStream_t stream) {
    char* ws = (char*)d_ws;
    int*   flag  = (int*)ws;
    u16*   xb    = (u16*)(ws + 256);
    u16*   Wqb   = (u16*)(ws + 256 + 25165824);
    u16*   Wob   = (u16*)(ws + 256 + 31457280);
    u16*   qkv   = (u16*)(ws + 256 + 33570816);
    u16*   y     = (u16*)(ws + 256 + 109068288);
    float2* tab  = (float2*)(ws + 256 + 134234112);

    prep_kernel<<<2048, 256, 0, stream>>>(d_in[0], xb, d_in[1], Wqb, d_in[3], Wob, tab, flag);

    // QKV GEMM (M=12288, N=3072): 256x256 tiles BK=64, natural grid (48,12), fused bias+RoPE
    gemm256p_kernel<256><<<dim3(48, 12), 512, 0, stream>>>(xb, Wqb, d_in[2], qkv, 3072, flag, 0, tab, 1);
    // Attention: QBLK=128, 1D grid 1536 with XCD-chunked (b,h) grouping
    attn_kernel<<<1536, 512, 0, stream>>>(qkv, y);
    // Output GEMM (M=12288, N=1024): 192x256 tiles, grid (64,4) = 256 blocks = 1 full round
    gemm256p_kernel<192><<<dim3(64, 4), 512, 0, stream>>>(y, Wob, d_in[4], d_out, 1024, flag, 1, tab, 0);
}

// Round 20
// 273.610 us; speedup vs baseline: 1.0999x; 1.0048x over previous
//
#include <hip/hip_runtime.h>
#include <hip/hip_bf16.h>

typedef __attribute__((ext_vector_type(8))) short bf16x8;   // 8 bf16 in 4 VGPRs
typedef __attribute__((ext_vector_type(4))) float f32x4;
typedef unsigned short u16;
typedef unsigned int u32;

#define DEV __device__ __forceinline__

DEV float bf2f(u16 v) { u32 u = ((u32)v) << 16; return __builtin_bit_cast(float, u); }
DEV u16 f2bf(float f) {
    u32 u = __builtin_bit_cast(u32, f);
    u32 r = (u + 0x7FFFu + ((u >> 16) & 1u)) >> 16;
    return (u16)r;
}
DEV u16 f2bf_trunc(float f) { return (u16)(__builtin_bit_cast(u32, f) >> 16); }

DEV void gll16(const u16* g, u16* l) {
    __builtin_amdgcn_global_load_lds((const __attribute__((address_space(1))) void*)g,
                                     (__attribute__((address_space(3))) void*)l, 16, 0, 0);
}

#define WAIT_VM0()   asm volatile("s_waitcnt vmcnt(0)" ::: "memory")
#define WAIT_LGKM0() asm volatile("s_waitcnt lgkmcnt(0)" ::: "memory")
#define BAR()        __builtin_amdgcn_s_barrier()
#define BARF()       asm volatile("s_barrier" ::: "memory")   // barrier + compiler mem fence

// ---------------------------------------------------------------------------
// Fused prep: self-detect dtype + cvt x/Wqkv/Wo to bf16 + rope table. 1 launch.
// (r15-verified) Each block detects independently; block 0 publishes *flag.
// ---------------------------------------------------------------------------
DEV void cvt8(const void* in, u16* out, int i, int fl) {
    if (fl) {
        ((bf16x8*)out)[i] = ((const bf16x8*)in)[i];
    } else {
        float4 a = ((const float4*)in)[2 * i], b = ((const float4*)in)[2 * i + 1];
        bf16x8 o;
        o[0] = (short)f2bf(a.x); o[1] = (short)f2bf(a.y);
        o[2] = (short)f2bf(a.z); o[3] = (short)f2bf(a.w);
        o[4] = (short)f2bf(b.x); o[5] = (short)f2bf(b.y);
        o[6] = (short)f2bf(b.z); o[7] = (short)f2bf(b.w);
        ((bf16x8*)out)[i] = o;
    }
}

__global__ void prep_kernel(const void* __restrict__ x, u16* __restrict__ xb,
                            const void* __restrict__ Wq, u16* __restrict__ Wqb,
                            const void* __restrict__ Wo, u16* __restrict__ Wob,
                            float2* __restrict__ tab, int* __restrict__ flag) {
    __shared__ int cnt;
    if (threadIdx.x == 0) cnt = 0;
    __syncthreads();
    {
        int c = 0;
        for (int i = threadIdx.x; i < 4096; i += 256) {
            u32 w = ((const u32*)x)[i];
            u32 e = (w >> 7) & 0xFF;
            c += (e >= 110 && e <= 132) ? 1 : 0;
        }
        atomicAdd(&cnt, c);
    }
    __syncthreads();
    const int fl = (cnt * 2 > 4096) ? 1 : 0;
    if (blockIdx.x == 0 && threadIdx.x == 0) *flag = fl;

    constexpr int N8X = 1572864, N8W = 393216, N8O = 131072;     // /8 elem counts
    constexpr int C1 = N8X, C2 = N8X + N8W, C3 = N8X + N8W + N8O;
    constexpr int TOTAL = C3 + 768 * 512;
    const int stride = gridDim.x * 256;
    for (int i = blockIdx.x * 256 + threadIdx.x; i < TOTAL; i += stride) {
        if (i < C1)       cvt8(x, xb, i, fl);
        else if (i < C2)  cvt8(Wq, Wqb, i - C1, fl);
        else if (i < C3)  cvt8(Wo, Wob, i - C2, fl);
        else {
            int r = i - C3;
            int t = r >> 9, j = r & 511;
            float freq = expf(-(float)(2 * j) * (9.210340371976184f / 1024.0f));
            float ang = (float)t * freq;
            tab[r] = make_float2(cosf(ang), sinf(ang));
        }
    }
}

// ---------------------------------------------------------------------------
// GEMM BMxBN tile, BK=64, 8 waves (2M x 4N), per-wave (BM/2)x(BN/4), 2-buf LDS,
// 4 phases per K-tile (r10/r13/r16-verified skeleton; BM/BN templated).
// QKV: <192,384> grid (64,8) = 512 blocks = exactly 2 dispatch rounds.
// Out-proj: <192,256> grid (64,4) = 256 blocks = 1 round (r19-verified).
// MH=BM/64 m-frags/half; NF=BN/64 n-frags; RoPE predicate per-16-col fragment
// (r17-verified: tiles can straddle col 2048).
// ---------------------------------------------------------------------------
template<int BM, int BN>
__global__ __launch_bounds__(512, 2)
void gemm256p_kernel(const u16* __restrict__ A, const u16* __restrict__ W,
                     const void* __restrict__ bias, void* __restrict__ C,
                     int N, const int* __restrict__ flag, int out_mode,
                     const float2* __restrict__ tab, int rope) {
    constexpr int K = 1024, NT = 16;
    constexpr int MH = BM / 64;                 // m-frags per half
    constexpr int NF = BN / 64;                 // n-frags per wave
    constexpr int NA = BM / 64;                 // A-stage gll16 calls (64 rows each)
    constexpr int NB = BN / 64;                 // B-stage gll16 calls
    constexpr int SBOFF = BM * 64;              // B offset within slot (u16)
    __shared__ u16 lds[2][BM * 64 + BN * 64];
    const int tid = threadIdx.x;
    const int l = tid & 63, w = tid >> 6;
    const int wm = w >> 2, wn = w & 3;          // 2M x 4N wave grid
    const int lo = l & 15, hi = l >> 4;

    const int M0 = blockIdx.x * BM, N0 = blockIdx.y * BN;

    const int rS = tid >> 3;                      // 0..63
    const int qS = (tid & 7) ^ (rS & 7);
    const u16* Ag = A + (size_t)(M0 + rS) * K + qS * 8;
    const u16* Wg = W + (size_t)(N0 + rS) * K + qS * 8;
    const int lb = w * 512;                       // wave-uniform u16 base within call-group

    f32x4 acc[2 * MH][NF] = {};

#define STG_A(kt, slot)                                                        \
    {                                                                          \
        u16* sA_ = &lds[slot][0];                                              \
        const u16* ga_ = Ag + (kt) * 64;                                       \
        _Pragma("unroll")                                                      \
        for (int hh = 0; hh < NA; ++hh)                                        \
            gll16(ga_ + (size_t)(64 * hh) * K, sA_ + hh * 4096 + lb);          \
    }
#define STG_B(kt, slot)                                                        \
    {                                                                          \
        u16* sB_ = &lds[slot][SBOFF];                                          \
        const u16* gb_ = Wg + (kt) * 64;                                       \
        _Pragma("unroll")                                                      \
        for (int hh = 0; hh < NB; ++hh)                                        \
            gll16(gb_ + (size_t)(64 * hh) * K, sB_ + hh * 4096 + lb);          \
    }

    STG_A(0, 0);
    STG_B(0, 0);
    WAIT_VM0();
    BARF();

    const int csw = lo & 7;

#pragma unroll 1
    for (int t = 0; t < NT; ++t) {
        const int cur = t & 1, nxt = cur ^ 1;
        const u16* sA = &lds[cur][0];
        const u16* sB = &lds[cur][SBOFF];
        bf16x8 afr[MH], bfr[NF];

        // ---- phase 0: ks=0, m-half 0 ----
#pragma unroll
        for (int n = 0; n < NF; ++n)
            bfr[n] = *(const bf16x8*)&sB[(wn * (BN / 4) + n * 16 + lo) * 64 + ((hi ^ csw) * 8)];
#pragma unroll
        for (int m = 0; m < MH; ++m)
            afr[m] = *(const bf16x8*)&sA[(wm * (BM / 2) + m * 16 + lo) * 64 + ((hi ^ csw) * 8)];
        if (t + 1 < NT) { STG_A(t + 1, nxt); }
        BARF();
        __builtin_amdgcn_s_setprio(1);
#pragma unroll
        for (int m = 0; m < MH; ++m)
#pragma unroll
            for (int n = 0; n < NF; ++n)
                acc[m][n] = __builtin_amdgcn_mfma_f32_16x16x32_bf16(afr[m], bfr[n], acc[m][n], 0, 0, 0);
        __builtin_amdgcn_s_setprio(0);
        BARF();

        // ---- phase 1: ks=0, m-half 1 ----
#pragma unroll
        for (int m = 0; m < MH; ++m)
            afr[m] = *(const bf16x8*)&sA[(wm * (BM / 2) + BM / 4 + m * 16 + lo) * 64 + ((hi ^ csw) * 8)];
        if (t + 1 < NT) { STG_B(t + 1, nxt); }
        BARF();
        __builtin_amdgcn_s_setprio(1);
#pragma unroll
        for (int m = 0; m < MH; ++m)
#pragma unroll
            for (int n = 0; n < NF; ++n)
                acc[MH + m][n] = __builtin_amdgcn_mfma_f32_16x16x32_bf16(afr[m], bfr[n], acc[MH + m][n], 0, 0, 0);
        __builtin_amdgcn_s_setprio(0);
        BARF();

        // ---- phase 2: ks=1, m-half 0 ----
#pragma unroll
        for (int n = 0; n < NF; ++n)
            bfr[n] = *(const bf16x8*)&sB[(wn * (BN / 4) + n * 16 + lo) * 64 + (((4 + hi) ^ csw) * 8)];
#pragma unroll
        for (int m = 0; m < MH; ++m)
            afr[m] = *(const bf16x8*)&sA[(wm * (BM / 2) + m * 16 + lo) * 64 + (((4 + hi) ^ csw) * 8)];
        BARF();
        __builtin_amdgcn_s_setprio(1);
#pragma unroll
        for (int m = 0; m < MH; ++m)
#pragma unroll
            for (int n = 0; n < NF; ++n)
                acc[m][n] = __builtin_amdgcn_mfma_f32_16x16x32_bf16(afr[m], bfr[n], acc[m][n], 0, 0, 0);
        __builtin_amdgcn_s_setprio(0);
        BARF();

        // ---- phase 3: ks=1, m-half 1 ----
#pragma unroll
        for (int m = 0; m < MH; ++m)
            afr[m] = *(const bf16x8*)&sA[(wm * (BM / 2) + BM / 4 + m * 16 + lo) * 64 + (((4 + hi) ^ csw) * 8)];
        WAIT_VM0();                              // own stage loads (issued ph0/ph1) confirmed
        BARF();
        __builtin_amdgcn_s_setprio(1);
#pragma unroll
        for (int m = 0; m < MH; ++m)
#pragma unroll
            for (int n = 0; n < NF; ++n)
                acc[MH + m][n] = __builtin_amdgcn_mfma_f32_16x16x32_bf16(afr[m], bfr[n], acc[MH + m][n], 0, 0, 0);
        __builtin_amdgcn_s_setprio(0);
        BARF();                                  // tile boundary: buf[nxt] globally ready
    }
#undef STG_A
#undef STG_B

    // epilogue: C/D layout col=lane&15, row=(lane>>4)*4+j  [m89-verified]
    const int fl = *flag;
    const int f32out = out_mode ? (fl == 0) : 0;
#pragma unroll
    for (int mi = 0; mi < 2 * MH; ++mi) {
        const int grp = mi / MH, idx = mi % MH;
        const int roff = wm * (BM / 2) + grp * (BM / 4) + idx * 16 + hi * 4;
        const int rbase = M0 + roff;
        const int tbase = (M0 % 768) + roff;     // BM | 768 => tile within one batch
#pragma unroll
        for (int n = 0; n < NF; ++n) {
            const int col = N0 + wn * (BN / 4) + lo + n * 16;
            float bi = fl ? bf2f(((const u16*)bias)[col]) : ((const float*)bias)[col];
            const int jf = (col & 1023) >> 1;
            const int odd = col & 1;
            const int do_rope = rope && (col < 2048);   // per-frag (16-aligned, wave-uniform)
#pragma unroll
            for (int j = 0; j < 4; ++j) {
                float v = acc[mi][n][j] + bi;
                if (do_rope) {
                    float partner = __shfl_xor(v, 1);   // adjacent column (lane lo^1)
                    float2 cs = tab[(tbase + j) * 512 + jf];
                    v = odd ? (v * cs.x + partner * cs.y) : (v * cs.x - partner * cs.y);
                }
                size_t idx2 = (size_t)(rbase + j) * N + col;
                if (f32out) ((float*)C)[idx2] = v;
                else        ((u16*)C)[idx2] = f2bf(v);
            }
        }
    }
}

// ---------------------------------------------------------------------------
// Flash attention, QBLK=128, 8 waves x 16 rows (r13-verified body).
// 1D grid 1536 with XCD-chunked remap (r16-verified, -16 us).
// ---------------------------------------------------------------------------
__global__ __launch_bounds__(512)
void attn_kernel(const u16* __restrict__ qkv, u16* __restrict__ y) {
    constexpr int T = 768, CH = 1024, QKVC = 3072;
    constexpr float NEG = -30000.0f;
    __shared__ u16 Ks[2][64 * 64];  // [key][d], cols XOR-swizzled by (key&7)*8
    __shared__ u16 Vt[64 * 72];     // [d][key], key-col XOR-swizzled by ((d>>3)&7)*8
    __shared__ u16 Ps[128 * 72];    // [q][key], stride-72

    const int tid = threadIdx.x, l = tid & 63, w = tid >> 6;   // w = 0..7
    const int hw = blockIdx.x;
    const int xcd = hw & 7, pos = hw >> 3;
    const int qt = pos % 6;
    const int g = (pos / 6) * 8 + xcd;          // (b,h) group, 0..255
    const int h = g & 15, b = g >> 4;
    const int lo = l & 15, hi = l >> 4;
    const int kk = hi * 8;
    const int swzk = (lo & 7) * 8;

    const int qrow = qt * 128 + w * 16 + lo;
    const u16* qptr = qkv + (size_t)(b * T + qrow) * QKVC + h * 64 + kk;
    bf16x8 aq0r = *(const bf16x8*)qptr;
    bf16x8 aq1r = *(const bf16x8*)(qptr + 32);
    bf16x8 aq0, aq1;
#pragma unroll
    for (int e = 0; e < 8; ++e) {
        aq0[e] = (short)f2bf(bf2f((u16)aq0r[e]) * 0.125f);
        aq1[e] = (short)f2bf(bf2f((u16)aq1r[e]) * 0.125f);
    }

    f32x4 o[4] = {};
    float mrun[4] = {NEG, NEG, NEG, NEG};
    float lrun[4] = {0.f, 0.f, 0.f, 0.f};    // per-lane PARTIAL row-sums (reduced in epilogue)

    const int ksr = w * 8 + (l >> 3);
    const int ksc = ((l & 7) ^ ((l >> 3) & 7)) * 8;
    const u16* kbase = qkv + (size_t)(b * T + ksr) * QKVC + CH + h * 64 + ksc;

    const int vd0 = (tid & 7) * 8;
    const int vswz = (tid & 7) * 8;
    const int vr0 = tid >> 3;                    // 0..63
    const u16* vbase = qkv + (size_t)(b * T) * QKVC + 2 * CH + h * 64 + vd0;

    const int NTk = 2 * qt + 2;                  // K-tiles for this block

    gll16(kbase, &Ks[0][w * 512]);
    bf16x8 cv0 = *(const bf16x8*)(vbase + (size_t)vr0 * QKVC);
    WAIT_VM0();
#pragma unroll
    for (int e = 0; e < 8; ++e)
        Vt[(vd0 + e) * 72 + (vr0 ^ vswz)] = (u16)cv0[e];

    for (int kt = 0; kt < NTk; ++kt) {
        const int cur = kt & 1, nxt = cur ^ 1;
        bf16x8 nv0;
        if (kt + 1 < NTk) {
            const size_t koff = (size_t)((kt + 1) * 64) * QKVC;
            gll16(kbase + koff, &Ks[nxt][w * 512]);
            nv0 = *(const bf16x8*)(vbase + (size_t)((kt + 1) * 64 + vr0) * QKVC);
        }
        WAIT_LGKM0();
        BAR();

        __builtin_amdgcn_s_setprio(1);
        f32x4 s[4];
#pragma unroll
        for (int n = 0; n < 4; ++n) {
            bf16x8 kb0 = *(const bf16x8*)&Ks[cur][(n * 16 + lo) * 64 + (kk ^ swzk)];
            bf16x8 kb1 = *(const bf16x8*)&Ks[cur][(n * 16 + lo) * 64 + ((32 + kk) ^ swzk)];
            f32x4 z = {0.f, 0.f, 0.f, 0.f};
            z = __builtin_amdgcn_mfma_f32_16x16x32_bf16(aq0, kb0, z, 0, 0, 0);
            z = __builtin_amdgcn_mfma_f32_16x16x32_bf16(aq1, kb1, z, 0, 0, 0);
            s[n] = z;
        }
        __builtin_amdgcn_s_setprio(0);

        if (kt >= 2 * qt) {   // diagonal-crossing tiles only
#pragma unroll
            for (int n = 0; n < 4; ++n) {
                int kcol = kt * 64 + n * 16 + lo;
#pragma unroll
                for (int j = 0; j < 4; ++j)
                    if (kcol > qt * 128 + w * 16 + hi * 4 + j) s[n][j] = NEG;
            }
        }
        float mx[4];
#pragma unroll
        for (int j = 0; j < 4; ++j) {
            float m0 = fmaxf(fmaxf(s[0][j], s[1][j]), fmaxf(s[2][j], s[3][j]));
            m0 = fmaxf(m0, __shfl_xor(m0, 1));
            m0 = fmaxf(m0, __shfl_xor(m0, 2));
            m0 = fmaxf(m0, __shfl_xor(m0, 4));
            m0 = fmaxf(m0, __shfl_xor(m0, 8));
            mx[j] = m0;
        }
        // defer-max: rescale only when some row grows by > 8
        float gg = fmaxf(fmaxf(mx[0] - mrun[0], mx[1] - mrun[1]),
                         fmaxf(mx[2] - mrun[2], mx[3] - mrun[3]));
        if (!__all(gg <= 8.0f)) {
#pragma unroll
            for (int j = 0; j < 4; ++j) {
                float mn = fmaxf(mrun[j], mx[j]);
                float c = __expf(mrun[j] - mn);
                mrun[j] = mn;
                lrun[j] *= c;
#pragma unroll
                for (int n = 0; n < 4; ++n) o[n][j] *= c;
            }
        }
        float p[4][4];
#pragma unroll
        for (int n = 0; n < 4; ++n)
#pragma unroll
            for (int j = 0; j < 4; ++j) {
                p[n][j] = __expf(s[n][j] - mrun[j]);
                Ps[(w * 16 + hi * 4 + j) * 72 + n * 16 + lo] = f2bf_trunc(p[n][j]);
            }
#pragma unroll
        for (int j = 0; j < 4; ++j)
            lrun[j] += p[0][j] + p[1][j] + p[2][j] + p[3][j];   // per-lane partial

        __builtin_amdgcn_s_setprio(1);
#pragma unroll
        for (int c = 0; c < 2; ++c) {
            bf16x8 pa = *(const bf16x8*)&Ps[(w * 16 + lo) * 72 + c * 32 + kk];
#pragma unroll
            for (int n = 0; n < 4; ++n) {
                const int v = (n * 2 + (lo >> 3)) & 7;
                bf16x8 vb = *(const bf16x8*)&Vt[(n * 16 + lo) * 72 + ((c * 32 + kk) ^ (v * 8))];
                o[n] = __builtin_amdgcn_mfma_f32_16x16x32_bf16(pa, vb, o[n], 0, 0, 0);
            }
        }
        __builtin_amdgcn_s_setprio(0);

        if (kt + 1 < NTk) {
            WAIT_VM0();
            BAR();
#pragma unroll
            for (int e = 0; e < 8; ++e)
                Vt[(vd0 + e) * 72 + (vr0 ^ vswz)] = (u16)nv0[e];
        }
    }

    // epilogue: reduce partial row-sums across the 16-lane row group, normalize
    float inv[4];
#pragma unroll
    for (int j = 0; j < 4; ++j) {
        float r = lrun[j];
        r += __shfl_xor(r, 1);
        r += __shfl_xor(r, 2);
        r += __shfl_xor(r, 4);
        r += __shfl_xor(r, 8);
        inv[j] = (r > 0.f) ? 1.0f / r : 0.f;
    }
#pragma unroll
    for (int n = 0; n < 4; ++n)
#pragma unroll
        for (int j = 0; j < 4; ++j) {
            int t = qt * 128 + w * 16 + hi * 4 + j;
            y[(size_t)(b * T + t) * CH + h * 64 + n * 16 + lo] = f2bf(o[n][j] * inv[j]);
        }
}

// ---------------------------------------------------------------------------
extern "C" void kernel_launch(void* const* d_in, const int* in_sizes, int n_in,
                              void* d_out, int out_size, void* d_ws, size_t ws_size,
                              hipStream_t stream) {
    char* ws = (char*)d_ws;
    int*   flag  = (int*)ws;
    u16*   xb    = (u16*)(ws + 256);
    u16*   Wqb   = (u16*)(ws + 256 + 25165824);
    u16*   Wob   = (u16*)(ws + 256 + 31457280);
    u16*   qkv   = (u16*)(ws + 256 + 33570816);
    u16*   y     = (u16*)(ws + 256 + 109068288);
    float2* tab  = (float2*)(ws + 256 + 134234112);

    prep_kernel<<<2048, 256, 0, stream>>>(d_in[0], xb, d_in[1], Wqb, d_in[3], Wob, tab, flag);

    // QKV GEMM (M=12288, N=3072): 192x384 tiles, grid (64,8) = 512 blocks = 2 full rounds
    gemm256p_kernel<192, 384><<<dim3(64, 8), 512, 0, stream>>>(xb, Wqb, d_in[2], qkv, 3072, flag, 0, tab, 1);
    // Attention: QBLK=128, 1D grid 1536 with XCD-chunked (b,h) grouping
    attn_kernel<<<1536, 512, 0, stream>>>(qkv, y);
    // Output GEMM (M=12288, N=1024): 192x256 tiles, grid (64,4) = 256 blocks = 1 full round
    gemm256p_kernel<192, 256><<<dim3(64, 4), 512, 0, stream>>>(y, Wob, d_in[4], d_out, 1024, flag, 1, tab, 0);
}